// Round 1
// baseline (345.190 us; speedup 1.0000x reference)
//
#include <hip/hip_runtime.h>
#include <cstdint>
#include <cstddef>

#define BB 32
#define EV 5
#define LL 130
#define HH 768
#define KK 21
#define LP 160   // padded L (10 x 16 MFMA tiles)

typedef __attribute__((ext_vector_type(8))) __bf16 bf16x8;
typedef __attribute__((ext_vector_type(4))) float f32x4;

__device__ __forceinline__ unsigned short f2bf(float f) {
    unsigned int u = __float_as_uint(f);
    u += 0x7FFFu + ((u >> 16) & 1u);   // RNE: critical so that ||hn||^2 stays ~1
    return (unsigned short)(u >> 16);
}
__device__ __forceinline__ float bf2f(unsigned int s) {
    return __uint_as_float(s << 16);
}

// ---------------------------------------------------------------------------
// K1: L2-normalize hiddens rows -> bf16, padded to LP rows per n (pad = 0)
// one wave per row, 4 rows per block
// ---------------------------------------------------------------------------
__global__ __launch_bounds__(256) void k_normalize(const float* __restrict__ hid,
                                                   unsigned short* __restrict__ hnbf) {
    int wave = threadIdx.x >> 6, lane = threadIdx.x & 63;
    int r = blockIdx.x * 4 + wave;          // 0 .. 160*160-1
    int n = r / LP, q = r % LP;
    unsigned short* dst = hnbf + (size_t)r * HH;
    if (q < LL) {
        const float4* s4 = (const float4*)(hid + ((size_t)n * LL + q) * HH);
        float4 v0 = s4[lane], v1 = s4[lane + 64], v2 = s4[lane + 128];
        float ss = v0.x*v0.x + v0.y*v0.y + v0.z*v0.z + v0.w*v0.w
                 + v1.x*v1.x + v1.y*v1.y + v1.z*v1.z + v1.w*v1.w
                 + v2.x*v2.x + v2.y*v2.y + v2.z*v2.z + v2.w*v2.w;
        #pragma unroll
        for (int m = 1; m < 64; m <<= 1) ss += __shfl_xor(ss, m, 64);
        float sc = 1.0f / fmaxf(sqrtf(ss), 1e-12f);
        ushort4 o0, o1, o2;
        o0.x = f2bf(v0.x*sc); o0.y = f2bf(v0.y*sc); o0.z = f2bf(v0.z*sc); o0.w = f2bf(v0.w*sc);
        o1.x = f2bf(v1.x*sc); o1.y = f2bf(v1.y*sc); o1.z = f2bf(v1.z*sc); o1.w = f2bf(v1.w*sc);
        o2.x = f2bf(v2.x*sc); o2.y = f2bf(v2.y*sc); o2.z = f2bf(v2.z*sc); o2.w = f2bf(v2.w*sc);
        ushort4* d4 = (ushort4*)dst;
        d4[lane] = o0; d4[lane + 64] = o1; d4[lane + 128] = o2;
    } else {
        ushort4 z; z.x = z.y = z.z = z.w = 0;
        ushort4* d4 = (ushort4*)dst;
        d4[lane] = z; d4[lane + 64] = z; d4[lane + 128] = z;
    }
}

// ---------------------------------------------------------------------------
// K1b: convert Wg1 to bf16
// ---------------------------------------------------------------------------
__global__ __launch_bounds__(256) void k_cvt_wg1(const float* __restrict__ w,
                                                 unsigned short* __restrict__ o) {
    int idx = blockIdx.x * 256 + threadIdx.x;
    if (idx < 128 * 1536) o[idx] = f2bf(w[idx]);
}

// K1c: fill pooled half of gating input matrix Xg[row = (b*5+i)*5+e][0:768]
__global__ __launch_bounds__(256) void k_xg_pooled(const float* __restrict__ pooled,
                                                   unsigned short* __restrict__ xg) {
    int row = blockIdx.x;                  // 0..799
    int bi = row / 5;                      // b*5+i
    const float* src = pooled + (size_t)bi * HH;
    unsigned short* dst = xg + (size_t)row * 1536;
    #pragma unroll
    for (int j = 0; j < 3; j++) { int h = threadIdx.x + j * 256; dst[h] = f2bf(src[h]); }
}

// ---------------------------------------------------------------------------
// K2a: batched similarity GEMM. block bid=(b*5+e)*5+i computes
// S[q][d] = hn[b,e][q,:] . hn[b,i][d,:]  (LPxLP, bf16 out)
// 4 waves in 2x2 grid, each wave 80x80 = 5x5 MFMA tiles, K=768 in steps of 32
// ---------------------------------------------------------------------------
__global__ __launch_bounds__(256) void k_sim_gemm(const unsigned short* __restrict__ hnbf,
                                                  unsigned short* __restrict__ Sg) {
    int bid = blockIdx.x;
    int b = bid / 25, e = (bid / 5) % 5, i = bid % 5;
    const unsigned short* A = hnbf + (size_t)(b * 5 + e) * LP * HH;
    const unsigned short* B = hnbf + (size_t)(b * 5 + i) * LP * HH;
    __shared__ unsigned short As[LP * 32];
    __shared__ unsigned short Bs[LP * 32];
    int tid = threadIdx.x, lane = tid & 63, wave = tid >> 6;
    int quad = lane >> 4, l16 = lane & 15;
    int wm = (wave & 1) * 5, wn = (wave >> 1) * 5;
    f32x4 acc[5][5];
    #pragma unroll
    for (int mt = 0; mt < 5; mt++)
        #pragma unroll
        for (int nt = 0; nt < 5; nt++) acc[mt][nt] = (f32x4){0.f, 0.f, 0.f, 0.f};

    for (int k0 = 0; k0 < HH; k0 += 32) {
        #pragma unroll
        for (int it = 0; it < 3; ++it) {
            int s = tid + it * 256;
            if (s < 640) {
                int row = s >> 2, sg = s & 3;
                *(uint4*)&As[s * 8] = *(const uint4*)(A + (size_t)row * HH + k0 + sg * 8);
                *(uint4*)&Bs[s * 8] = *(const uint4*)(B + (size_t)row * HH + k0 + sg * 8);
            }
        }
        __syncthreads();
        bf16x8 af[5], bfr[5];
        #pragma unroll
        for (int t = 0; t < 5; t++) {
            af[t]  = *(const bf16x8*)&As[((wm + t) * 16 + l16) * 32 + quad * 8];
            bfr[t] = *(const bf16x8*)&Bs[((wn + t) * 16 + l16) * 32 + quad * 8];
        }
        #pragma unroll
        for (int mt = 0; mt < 5; mt++)
            #pragma unroll
            for (int nt = 0; nt < 5; nt++)
                acc[mt][nt] = __builtin_amdgcn_mfma_f32_16x16x32_bf16(af[mt], bfr[nt], acc[mt][nt], 0, 0, 0);
        __syncthreads();
    }
    size_t base = (size_t)bid * LP * LP;
    #pragma unroll
    for (int mt = 0; mt < 5; mt++)
        #pragma unroll
        for (int nt = 0; nt < 5; nt++) {
            int R = (wm + mt) * 16 + quad * 4;      // + reg -> q
            int C = (wn + nt) * 16 + l16;           // d
            unsigned short* dst = Sg + base + (size_t)R * LP + C;
            #pragma unroll
            for (int reg = 0; reg < 4; reg++) dst[(size_t)reg * LP] = f2bf(acc[mt][nt][reg]);
        }
}

// ---------------------------------------------------------------------------
// K2b: fused kernel-pool + log + W_att dot -> score; diag blocks also produce sel
// Gaussian-grid trick: exp(-50(s-mu_k)^2) = C_k * u * r^(k-1),
//   u=exp(-50 s^2+95 s), r=exp(-10 s), C_k=exp(-50 mu_k^2);  k=0 handled direct.
// ---------------------------------------------------------------------------
#define SLS 168   // padded LDS row stride (floats) for S chunk

template <bool DIAG>
__device__ __forceinline__ void pool_body(
    int b, int e, int i, int ne, int ni,
    const unsigned short* __restrict__ Sg,
    const int* __restrict__ msk, const int* __restrict__ seg,
    const float* __restrict__ Watt, const float* __restrict__ batt,
    const float* __restrict__ Wsel, const float* __restrict__ bsel,
    float* __restrict__ score, float* __restrict__ sel,
    float* Sl, float* wdA, float* wdE, float* wqC,
    float* WaL, float* WsL, float* CkL, float* redw) {

    const float LOG2E = 1.4426950408889634f;
    const float CA = -50.0f * LOG2E;
    const float CB = 95.0f * LOG2E;
    const float CR = -10.0f * LOG2E;
    const float C0 = -500000.0f * LOG2E;
    int tid = threadIdx.x;
    int bid = blockIdx.x;

    if (tid < LP) {
        int d = tid;
        float mtI = (d >= 1 && d < LL) ? (float)msk[ni * LL + d] : 0.0f;
        wdA[d] = mtI;
        float mtE = (d >= 1 && d < LL) ? (float)msk[ne * LL + d] : 0.0f;
        float sgE = (d < LL) ? (float)seg[ne * LL + d] : 0.0f;
        wdE[d] = sgE * mtE;                  // mask_ev for evidence ne
        wqC[d] = (1.0f - sgE) * mtE;         // mask_claim for evidence ne
    }
    if (tid < KK) {
        WaL[tid] = Watt[tid];
        WsL[tid] = Wsel[tid];
        float mu = 0.95f - 0.1f * (tid - 1);
        CkL[tid] = (tid == 0) ? 1.0f : exp2f(CA * mu * mu);
    }
    __syncthreads();

    float selAcc = 0.0f;
    for (int qb = 0; qb < LP; qb += 64) {
        int nrows = (LP - qb) < 64 ? (LP - qb) : 64;
        int nseg = nrows * 20;               // 20 x uint4 (8 bf16) per row
        for (int s = tid; s < nseg; s += 256) {
            int row = s / 20, sg = s % 20;
            uint4 v = *(const uint4*)(Sg + (size_t)bid * LP * LP + (size_t)(qb + row) * LP + sg * 8);
            float* o = &Sl[row * SLS + sg * 8];
            o[0] = bf2f(v.x & 0xFFFFu); o[1] = bf2f(v.x >> 16);
            o[2] = bf2f(v.y & 0xFFFFu); o[3] = bf2f(v.y >> 16);
            o[4] = bf2f(v.z & 0xFFFFu); o[5] = bf2f(v.z >> 16);
            o[6] = bf2f(v.w & 0xFFFFu); o[7] = bf2f(v.w >> 16);
        }
        __syncthreads();

        int q = qb + (tid >> 2), dg = tid & 3;
        float acc[KK], acc2[KK];
        #pragma unroll
        for (int k = 0; k < KK; k++) { acc[k] = 0.0f; acc2[k] = 0.0f; }

        if (q < LP) {
            const float* srow = &Sl[(tid >> 2) * SLS];
            for (int j = 0; j < 10; j++) {
                int d0 = (dg + 4 * j) * 4;
                float4 sv = *(const float4*)&srow[d0];
                #pragma unroll
                for (int u = 0; u < 4; u++) {
                    float s = (u == 0) ? sv.x : (u == 1) ? sv.y : (u == 2) ? sv.z : sv.w;
                    int d = d0 + u;
                    float w = wdA[d];
                    float w2 = DIAG ? wdE[d] : 0.0f;
                    float s2 = s * s;
                    float pe = exp2f(fmaf(CB, s, CA * s2));
                    float rr = exp2f(CR * s);
                    float sm1 = s - 1.0f;
                    float e0 = exp2f(C0 * (sm1 * sm1));
                    acc[0] = fmaf(w, e0, acc[0]);
                    if (DIAG) acc2[0] = fmaf(w2, e0, acc2[0]);
                    float p = pe;
                    #pragma unroll
                    for (int k = 1; k < KK; k++) {
                        acc[k] = fmaf(w, p, acc[k]);
                        if (DIAG) acc2[k] = fmaf(w2, p, acc2[k]);
                        p *= rr;
                    }
                }
            }
        }
        // reduce the 4 d-phases (lanes 4g..4g+3, same wave)
        #pragma unroll
        for (int k = 0; k < KK; k++) {
            acc[k] += __shfl_xor(acc[k], 1, 64);
            acc[k] += __shfl_xor(acc[k], 2, 64);
            if (DIAG) {
                acc2[k] += __shfl_xor(acc2[k], 1, 64);
                acc2[k] += __shfl_xor(acc2[k], 2, 64);
            }
        }
        if (q < LP && dg == 0) {
            float sc = batt[0];
            #pragma unroll
            for (int k = 0; k < KK; k++) {
                float ps = fmaxf(CkL[k] * acc[k], 1e-10f);
                sc += WaL[k] * __logf(ps);
            }
            score[(size_t)((b * 5 + i) * 5 + e) * LP + q] = sc;
            if (DIAG) {
                float cq = 0.0f;
                #pragma unroll
                for (int k = 0; k < KK; k++) {
                    float ps = fmaxf(CkL[k] * acc2[k], 1e-10f);
                    cq += WsL[k] * __logf(ps);
                }
                selAcc += wqC[q] * cq;
            }
        }
        __syncthreads();
    }
    if (DIAG) {
        #pragma unroll
        for (int m = 1; m < 64; m <<= 1) selAcc += __shfl_xor(selAcc, m, 64);
        if ((tid & 63) == 0) redw[tid >> 6] = selAcc;
        __syncthreads();
        if (tid == 0) {
            float tot = redw[0] + redw[1] + redw[2] + redw[3];
            float D = 0.0f;
            for (int d = 0; d < LP; d++) D += wqC[d];
            sel[ne] = bsel[0] + tot / (D + 1e-10f);
        }
    }
}

__global__ __launch_bounds__(256) void k_pool(const unsigned short* __restrict__ Sg,
        const int* __restrict__ msk, const int* __restrict__ seg,
        const float* __restrict__ Watt, const float* __restrict__ batt,
        const float* __restrict__ Wsel, const float* __restrict__ bsel,
        float* __restrict__ score, float* __restrict__ sel) {
    __shared__ float Sl[64 * SLS];
    __shared__ float wdA[LP], wdE[LP], wqC[LP];
    __shared__ float WaL[KK], WsL[KK], CkL[KK];
    __shared__ float redw[4];
    int bid = blockIdx.x;
    int b = bid / 25, e = (bid / 5) % 5, i = bid % 5;
    int ne = b * 5 + e, ni = b * 5 + i;
    if (e == i)
        pool_body<true>(b, e, i, ne, ni, Sg, msk, seg, Watt, batt, Wsel, bsel,
                        score, sel, Sl, wdA, wdE, wqC, WaL, WsL, CkL, redw);
    else
        pool_body<false>(b, e, i, ne, ni, Sg, msk, seg, Watt, batt, Wsel, bsel,
                         score, sel, Sl, wdA, wdE, wqC, WaL, WsL, CkL, redw);
}

// ---------------------------------------------------------------------------
// K3: per (b,e): masked softmax over q of score for each i, then
// denoise_i[b,e,:] = sum_q att_i[q] * hiddens[b,e,q,:]  (single pass over hiddens)
// also writes bf16 denoise into gating matrix Xg[row][768:1536]
// ---------------------------------------------------------------------------
__global__ __launch_bounds__(256) void k_att_denoise(const float* __restrict__ score,
        const float* __restrict__ hid, const int* __restrict__ msk,
        float* __restrict__ denoise, unsigned short* __restrict__ xg) {
    int be = blockIdx.x;                 // b*5+e
    int b = be / 5, e = be % 5;
    __shared__ float att[5][LL];
    __shared__ float red[256];
    int tid = threadIdx.x;

    for (int i = 0; i < 5; i++) {
        float val = -1e30f;
        if (tid < LL) {
            float mt = (tid >= 1) ? (float)msk[be * LL + tid] : 0.0f;
            float raw = score[(size_t)((b * 5 + i) * 5 + e) * LP + tid];
            val = (mt > 0.0f) ? raw : -1e4f;
        }
        red[tid] = val; __syncthreads();
        for (int s = 128; s > 0; s >>= 1) {
            if (tid < s) red[tid] = fmaxf(red[tid], red[tid + s]);
            __syncthreads();
        }
        float mx = red[0]; __syncthreads();
        float ex = (tid < LL) ? __expf(val - mx) : 0.0f;
        red[tid] = ex; __syncthreads();
        for (int s = 128; s > 0; s >>= 1) {
            if (tid < s) red[tid] += red[tid + s];
            __syncthreads();
        }
        float Z = red[0]; __syncthreads();
        if (tid < LL) att[i][tid] = ex / Z;
    }
    __syncthreads();

    float acc[5][3];
    #pragma unroll
    for (int i = 0; i < 5; i++)
        #pragma unroll
        for (int j = 0; j < 3; j++) acc[i][j] = 0.0f;

    for (int q = 0; q < LL; q++) {
        float w0 = att[0][q], w1 = att[1][q], w2 = att[2][q], w3 = att[3][q], w4 = att[4][q];
        #pragma unroll
        for (int j = 0; j < 3; j++) {
            float hv = hid[((size_t)be * LL + q) * HH + tid + j * 256];
            acc[0][j] += w0 * hv; acc[1][j] += w1 * hv; acc[2][j] += w2 * hv;
            acc[3][j] += w3 * hv; acc[4][j] += w4 * hv;
        }
    }
    #pragma unroll
    for (int i = 0; i < 5; i++)
        #pragma unroll
        for (int j = 0; j < 3; j++) {
            int h = tid + j * 256;
            float v = acc[i][j];
            denoise[(((size_t)i * BB + b) * 5 + e) * HH + h] = v;
            xg[(size_t)((b * 5 + i) * 5 + e) * 1536 + HH + h] = f2bf(v);
        }
}

// ---------------------------------------------------------------------------
// K4: gating GEMM  Cg[800][128] = Xg[800][1536] @ Wg1^T  (bf16 MFMA)
// block: 32 rows x 128 cols; waves 2x2 (16 rows x 64 cols each)
// ---------------------------------------------------------------------------
__global__ __launch_bounds__(256) void k_gate_gemm(const unsigned short* __restrict__ xg,
        const unsigned short* __restrict__ wg1b, float* __restrict__ cg) {
    int m0 = blockIdx.x * 32;
    __shared__ unsigned short As[32 * 32];
    __shared__ unsigned short Bs[128 * 32];
    int tid = threadIdx.x, lane = tid & 63, wave = tid >> 6;
    int quad = lane >> 4, l16 = lane & 15;
    int wm = wave & 1, wnb = (wave >> 1) * 4;
    f32x4 acc[4];
    #pragma unroll
    for (int nt = 0; nt < 4; nt++) acc[nt] = (f32x4){0.f, 0.f, 0.f, 0.f};

    for (int k0 = 0; k0 < 1536; k0 += 32) {
        if (tid < 128) {
            int row = tid >> 2, sg = tid & 3;
            *(uint4*)&As[tid * 8] = *(const uint4*)(xg + (size_t)(m0 + row) * 1536 + k0 + sg * 8);
        }
        #pragma unroll
        for (int it = 0; it < 2; it++) {
            int s = tid + it * 256;
            int row = s >> 2, sg = s & 3;
            *(uint4*)&Bs[s * 8] = *(const uint4*)(wg1b + (size_t)row * 1536 + k0 + sg * 8);
        }
        __syncthreads();
        bf16x8 af = *(const bf16x8*)&As[(wm * 16 + l16) * 32 + quad * 8];
        #pragma unroll
        for (int nt = 0; nt < 4; nt++) {
            bf16x8 bfr = *(const bf16x8*)&Bs[((wnb + nt) * 16 + l16) * 32 + quad * 8];
            acc[nt] = __builtin_amdgcn_mfma_f32_16x16x32_bf16(af, bfr, acc[nt], 0, 0, 0);
        }
        __syncthreads();
    }
    #pragma unroll
    for (int nt = 0; nt < 4; nt++)
        #pragma unroll
        for (int reg = 0; reg < 4; reg++) {
            int R = m0 + wm * 16 + quad * 4 + reg;
            int C = (wnb + nt) * 16 + l16;
            cg[(size_t)R * 128 + C] = acc[nt][reg];
        }
}

// ---------------------------------------------------------------------------
// K5: per (b,i): g[e] = Wg2 . relu(Cg_row + bg1) + bg2 ; w_de = softmax_e ;
// de = sum_e w_de[e]*denoise ; feat[c] = concat(pooled,de) . Wd[c] + bd[c]
// ---------------------------------------------------------------------------
__global__ __launch_bounds__(256) void k_gate_epilogue(const float* __restrict__ cg,
        const float* __restrict__ bg1, const float* __restrict__ wg2,
        const float* __restrict__ bg2, const float* __restrict__ denoise,
        const float* __restrict__ pooled, const float* __restrict__ wd,
        const float* __restrict__ bd, float* __restrict__ feat) {
    int bi = blockIdx.x;                 // b*5+i
    int b = bi / 5, i = bi % 5;
    __shared__ float red[256];
    __shared__ float gL[5];
    __shared__ float deL[HH];
    int tid = threadIdx.x;

    for (int e = 0; e < 5; e++) {
        float v = 0.0f;
        if (tid < 128) {
            float c = cg[(size_t)(bi * 5 + e) * 128 + tid] + bg1[tid];
            v = wg2[tid] * fmaxf(c, 0.0f);
        }
        red[tid] = v; __syncthreads();
        for (int s = 128; s > 0; s >>= 1) {
            if (tid < s) red[tid] += red[tid + s];
            __syncthreads();
        }
        if (tid == 0) gL[e] = red[0] + bg2[0];
        __syncthreads();
    }
    float m = gL[0];
    #pragma unroll
    for (int e = 1; e < 5; e++) m = fmaxf(m, gL[e]);
    float wde[5]; float z = 0.0f;
    #pragma unroll
    for (int e = 0; e < 5; e++) { wde[e] = __expf(gL[e] - m); z += wde[e]; }
    #pragma unroll
    for (int e = 0; e < 5; e++) wde[e] /= z;

    #pragma unroll
    for (int j = 0; j < 3; j++) {
        int h = tid + j * 256;
        float v = 0.0f;
        #pragma unroll
        for (int e = 0; e < 5; e++)
            v += wde[e] * denoise[(((size_t)i * BB + b) * 5 + e) * HH + h];
        deL[h] = v;
    }
    __syncthreads();

    float part[3] = {0.0f, 0.0f, 0.0f};
    for (int mm = 0; mm < 6; mm++) {
        int h = tid + mm * 256;
        float x = (h < HH) ? pooled[(size_t)bi * HH + h] : deL[h - HH];
        #pragma unroll
        for (int c = 0; c < 3; c++) part[c] += x * wd[(size_t)c * 1536 + h];
    }
    for (int c = 0; c < 3; c++) {
        red[tid] = part[c]; __syncthreads();
        for (int s = 128; s > 0; s >>= 1) {
            if (tid < s) red[tid] += red[tid + s];
            __syncthreads();
        }
        if (tid == 0) feat[bi * 3 + c] = red[0] + bd[c];
        __syncthreads();
    }
}

// ---------------------------------------------------------------------------
// K6: final combine: select softmax over i, class softmax over c, log(prob)
// ---------------------------------------------------------------------------
__global__ __launch_bounds__(64) void k_final(const float* __restrict__ sel,
        const float* __restrict__ feat, float* __restrict__ out) {
    int b = threadIdx.x;
    if (b >= BB) return;
    float sv[5]; float m = -1e30f;
    #pragma unroll
    for (int i = 0; i < 5; i++) { sv[i] = sel[b * 5 + i]; m = fmaxf(m, sv[i]); }
    float z = 0.0f;
    #pragma unroll
    for (int i = 0; i < 5; i++) { sv[i] = __expf(sv[i] - m); z += sv[i]; }
    #pragma unroll
    for (int i = 0; i < 5; i++) sv[i] /= z;
    float prob[3] = {0.0f, 0.0f, 0.0f};
    #pragma unroll
    for (int i = 0; i < 5; i++) {
        float f0 = feat[(b * 5 + i) * 3 + 0];
        float f1 = feat[(b * 5 + i) * 3 + 1];
        float f2 = feat[(b * 5 + i) * 3 + 2];
        float mm = fmaxf(f0, fmaxf(f1, f2));
        float e0 = __expf(f0 - mm), e1 = __expf(f1 - mm), e2 = __expf(f2 - mm);
        float zz = e0 + e1 + e2;
        prob[0] += sv[i] * e0 / zz;
        prob[1] += sv[i] * e1 / zz;
        prob[2] += sv[i] * e2 / zz;
    }
    #pragma unroll
    for (int c = 0; c < 3; c++) out[b * 3 + c] = __logf(prob[c]);
}

// ---------------------------------------------------------------------------
extern "C" void kernel_launch(void* const* d_in, const int* in_sizes, int n_in,
                              void* d_out, int out_size, void* d_ws, size_t ws_size,
                              hipStream_t stream) {
    const float* hiddens = (const float*)d_in[0];
    const float* pooled  = (const float*)d_in[1];
    const int*   msk     = (const int*)d_in[2];
    const int*   seg     = (const int*)d_in[3];
    const float* Watt    = (const float*)d_in[4];
    const float* batt    = (const float*)d_in[5];
    const float* Wsel    = (const float*)d_in[6];
    const float* bsel    = (const float*)d_in[7];
    const float* Wg1     = (const float*)d_in[8];
    const float* bg1     = (const float*)d_in[9];
    const float* Wg2     = (const float*)d_in[10];
    const float* bg2     = (const float*)d_in[11];
    const float* Wd      = (const float*)d_in[12];
    const float* bd      = (const float*)d_in[13];

    char* ws = (char*)d_ws;
    size_t off = 0;
    auto alloc = [&](size_t bytes) -> void* {
        void* p = ws + off;
        off += (bytes + 255) & ~(size_t)255;
        return p;
    };
    unsigned short* hnbf   = (unsigned short*)alloc((size_t)160 * LP * HH * 2);  // 39.3 MB
    unsigned short* Sg     = (unsigned short*)alloc((size_t)800 * LP * LP * 2);  // 41.0 MB
    float*          score  = (float*)alloc((size_t)800 * LP * 4);
    float*          sel    = (float*)alloc((size_t)160 * 4);
    float*          denoise= (float*)alloc((size_t)5 * BB * 5 * HH * 4);
    unsigned short* xg     = (unsigned short*)alloc((size_t)800 * 1536 * 2);
    unsigned short* wg1b   = (unsigned short*)alloc((size_t)128 * 1536 * 2);
    float*          cg     = (float*)alloc((size_t)800 * 128 * 4);
    float*          feat   = (float*)alloc((size_t)800 * 3 * 4);
    (void)ws_size; (void)in_sizes; (void)n_in; (void)out_size;

    k_normalize<<<dim3(160 * LP / 4), dim3(256), 0, stream>>>(hiddens, hnbf);
    k_cvt_wg1<<<dim3(768), dim3(256), 0, stream>>>(Wg1, wg1b);
    k_xg_pooled<<<dim3(800), dim3(256), 0, stream>>>(pooled, xg);
    k_sim_gemm<<<dim3(800), dim3(256), 0, stream>>>(hnbf, Sg);
    k_pool<<<dim3(800), dim3(256), 0, stream>>>(Sg, msk, seg, Watt, batt, Wsel, bsel, score, sel);
    k_att_denoise<<<dim3(160), dim3(256), 0, stream>>>(score, hiddens, msk, denoise, xg);
    k_gate_gemm<<<dim3(25), dim3(256), 0, stream>>>(xg, wg1b, cg);
    k_gate_epilogue<<<dim3(160), dim3(256), 0, stream>>>(cg, bg1, Wg2, bg2, denoise, pooled, Wd, bd, feat);
    k_final<<<dim3(1), dim3(64), 0, stream>>>(sel, feat, (float*)d_out);
}